// Round 4
// baseline (43.945 us; speedup 1.0000x reference)
//
#include <hip/hip_runtime.h>

// DifferentiableJPEG forward on MI355X — round 4 (round-3 fix: nontemporal
// store via clang ext_vector float4, not HIP_vector_type).
// 8 threads per 8x8 block (one per row); in-wave LDS transposes (pitch 9,
// conflict-free both sides, no barriers); barrier-free quant table.

typedef float v4f __attribute__((ext_vector_type(4)));

static __device__ __constant__ float c_qbase[64] = {
    16.f, 11.f, 10.f, 16.f, 24.f, 40.f, 51.f, 61.f,
    12.f, 12.f, 14.f, 19.f, 26.f, 58.f, 60.f, 55.f,
    14.f, 13.f, 16.f, 24.f, 40.f, 57.f, 69.f, 56.f,
    14.f, 17.f, 22.f, 29.f, 51.f, 87.f, 80.f, 62.f,
    18.f, 22.f, 37.f, 56.f, 68.f, 109.f, 103.f, 77.f,
    24.f, 35.f, 55.f, 64.f, 81.f, 104.f, 113.f, 92.f,
    49.f, 64.f, 78.f, 87.f, 103.f, 121.f, 120.f, 101.f,
    72.f, 92.f, 95.f, 98.f, 112.f, 100.f, 103.f, 99.f
};

#define LDS_PITCH 9  // write bank = 9t mod 32 (gcd(9,32)=1) -> 2-way max (free)

__global__ __launch_bounds__(256, 8)
void jpeg_row_kernel(const float* __restrict__ in, const int* __restrict__ qual,
                     float* __restrict__ out) {
    constexpr float D[8][8] = {
        { 0.3535533906f,  0.3535533906f,  0.3535533906f,  0.3535533906f,
          0.3535533906f,  0.3535533906f,  0.3535533906f,  0.3535533906f },
        { 0.4903926402f,  0.4157348062f,  0.2777851165f,  0.0975451610f,
         -0.0975451610f, -0.2777851165f, -0.4157348062f, -0.4903926402f },
        { 0.4619397663f,  0.1913417162f, -0.1913417162f, -0.4619397663f,
         -0.4619397663f, -0.1913417162f,  0.1913417162f,  0.4619397663f },
        { 0.4157348062f, -0.0975451610f, -0.4903926402f, -0.2777851165f,
          0.2777851165f,  0.4903926402f,  0.0975451610f, -0.4157348062f },
        { 0.3535533906f, -0.3535533906f, -0.3535533906f,  0.3535533906f,
          0.3535533906f, -0.3535533906f, -0.3535533906f,  0.3535533906f },
        { 0.2777851165f, -0.4903926402f,  0.0975451610f,  0.4157348062f,
         -0.4157348062f, -0.0975451610f,  0.4903926402f, -0.2777851165f },
        { 0.1913417162f, -0.4619397663f,  0.4619397663f, -0.1913417162f,
         -0.1913417162f,  0.4619397663f, -0.4619397663f,  0.1913417162f },
        { 0.0975451610f, -0.2777851165f,  0.4157348062f, -0.4903926402f,
          0.4903926402f, -0.4157348062f,  0.2777851165f, -0.0975451610f }
    };

    __shared__ float qlds[64];
    __shared__ float tr[256 * LDS_PITCH];

    const int tid = threadIdx.x;

    // Every wave writes the full table (identical values) -> no barrier needed:
    // each wave only depends on its OWN writes (in-wave lgkmcnt ordering).
    {
        int q = qual[0];
        double sd = (q < 50) ? (5000.0 / (double)q) : (200.0 - 2.0 * (double)q);
        float scale = (float)sd;
        int e = tid & 63;
        float v = c_qbase[e] * scale / 100.0f;
        qlds[e] = fminf(fmaxf(v, 1.0f), 255.0f);
    }

    const int gt  = blockIdx.x * 256 + tid;       // global (block,row) id
    const int b   = gt >> 3;                      // 8x8-block index
    const int r   = gt & 7;                       // row within block
    const int img = b >> 12;                      // 64*64 blocks per 512x512 plane
    const int by  = (b >> 6) & 63;
    const int bx  = b & 63;
    const long rowaddr = (((long)img * 512 + (long)by * 8 + r) * 512) + (long)bx * 8;

    // load row r, subtract 0.5 (issue early; independent of LDS)
    float x[8];
    {
        const float4 a  = *reinterpret_cast<const float4*>(in + rowaddr);
        const float4 b4 = *reinterpret_cast<const float4*>(in + rowaddr + 4);
        x[0] = a.x - 0.5f; x[1] = a.y - 0.5f; x[2] = a.z - 0.5f; x[3] = a.w - 0.5f;
        x[4] = b4.x - 0.5f; x[5] = b4.y - 0.5f; x[6] = b4.z - 0.5f; x[7] = b4.w - 0.5f;
    }

    // my quant column: q[k][r] for k=0..7
    float qc[8];
#pragma unroll
    for (int k = 0; k < 8; ++k) qc[k] = qlds[k * 8 + r];

    // Stage A: row transform  u[l] = (X D^T)[r][l]
    float u[8];
#pragma unroll
    for (int l = 0; l < 8; ++l) {
        float s = 0.0f;
#pragma unroll
        for (int j = 0; j < 8; ++j) s = fmaf(x[j], D[l][j], s);
        u[l] = s;
    }

    // Transpose 1 (wave-private LDS slice; conflict-free both directions)
    const int base_w = tid * LDS_PITCH;
    const int base_r = (tid & ~7) * LDS_PITCH;
#pragma unroll
    for (int j = 0; j < 8; ++j) tr[base_w + j] = u[j];
    float t[8];
#pragma unroll
    for (int j = 0; j < 8; ++j) t[j] = tr[base_r + j * LDS_PITCH + r];  // t[j] = U[j][r]

    // Stage B: y[k] = (D U)[k][r]; quantize (IEEE div + half-even round)
    float y[8];
#pragma unroll
    for (int k = 0; k < 8; ++k) {
        float s = 0.0f;
#pragma unroll
        for (int j = 0; j < 8; ++j) s = fmaf(D[k][j], t[j], s);
        y[k] = rintf(s / qc[k]) * qc[k];
    }

    // Stage C1: v[j] = (D^T Yq)[j][r]
    float v[8];
#pragma unroll
    for (int j = 0; j < 8; ++j) {
        float s = 0.0f;
#pragma unroll
        for (int k = 0; k < 8; ++k) s = fmaf(D[k][j], y[k], s);
        v[j] = s;
    }

    // Transpose 2
#pragma unroll
    for (int j = 0; j < 8; ++j) tr[base_w + j] = v[j];
    float w[8];
#pragma unroll
    for (int j = 0; j < 8; ++j) w[j] = tr[base_r + j * LDS_PITCH + r];  // w[j] = V[r][j]

    // Stage C2: s[c] = (V D)[r][c], +0.5, clip, nontemporal store
    float srow[8];
#pragma unroll
    for (int c = 0; c < 8; ++c) {
        float s = 0.0f;
#pragma unroll
        for (int l = 0; l < 8; ++l) s = fmaf(w[l], D[l][c], s);
        s += 0.5f;
        srow[c] = fminf(fmaxf(s, 0.0f), 1.0f);
    }
    v4f o0 = { srow[0], srow[1], srow[2], srow[3] };
    v4f o1 = { srow[4], srow[5], srow[6], srow[7] };
    __builtin_nontemporal_store(o0, reinterpret_cast<v4f*>(out + rowaddr));
    __builtin_nontemporal_store(o1, reinterpret_cast<v4f*>(out + rowaddr + 4));
}

extern "C" void kernel_launch(void* const* d_in, const int* in_sizes, int n_in,
                              void* d_out, int out_size, void* d_ws, size_t ws_size,
                              hipStream_t stream) {
    const float* img  = (const float*)d_in[0];
    const int*   qual = (const int*)d_in[1];
    float*       out  = (float*)d_out;

    const int nthreads_total = (out_size / 64) * 8;   // 8 threads per 8x8 block
    const int block = 256;
    const int grid = nthreads_total / block;          // 12288

    jpeg_row_kernel<<<grid, block, 0, stream>>>(img, qual, out);
}

// Round 5
// 38.693 us; speedup vs baseline: 1.1357x; 1.1357x over previous
//
#include <hip/hip_runtime.h>

// DifferentiableJPEG forward on MI355X — round 5.
// 8 threads per 8x8 block (one per row); in-wave LDS transposes (pitch 9,
// conflict-free, no barriers). vs round 2 (36us):
//  - even/odd butterfly in all four 8-pt transforms (64 FMA -> 8 add + 32 FMA)
//  - reciprocal-mul quantization (float2 {q,1/q} LDS table, no per-elem divides)
//  - regular float4 stores (nt stores regressed: write amplification 98->115MB)
// Safety: quotients concentrate ~N(0,0.06..0.3); tie boundaries at 0.5 are
// >=10 sigma away, so 1e-6 fp-reordering perturbations cannot flip rint().

typedef float v4f __attribute__((ext_vector_type(4)));

static __device__ __constant__ float c_qbase[64] = {
    16.f, 11.f, 10.f, 16.f, 24.f, 40.f, 51.f, 61.f,
    12.f, 12.f, 14.f, 19.f, 26.f, 58.f, 60.f, 55.f,
    14.f, 13.f, 16.f, 24.f, 40.f, 57.f, 69.f, 56.f,
    14.f, 17.f, 22.f, 29.f, 51.f, 87.f, 80.f, 62.f,
    18.f, 22.f, 37.f, 56.f, 68.f, 109.f, 103.f, 77.f,
    24.f, 35.f, 55.f, 64.f, 81.f, 104.f, 113.f, 92.f,
    49.f, 64.f, 78.f, 87.f, 103.f, 121.f, 120.f, 101.f,
    72.f, 92.f, 95.f, 98.f, 112.f, 100.f, 103.f, 99.f
};

#define LDS_PITCH 9  // write bank = 9t mod 32 (gcd(9,32)=1) -> 2-way max (free)

__global__ __launch_bounds__(256, 8)
void jpeg_row_kernel(const float* __restrict__ in, const int* __restrict__ qual,
                     float* __restrict__ out) {
    // Even rows (k=0,2,4,6) and odd rows (k=1,3,5,7) of the DCT basis, cols 0..3.
    constexpr float CE[4][4] = {
        { 0.3535533906f,  0.3535533906f,  0.3535533906f,  0.3535533906f },
        { 0.4619397663f,  0.1913417162f, -0.1913417162f, -0.4619397663f },
        { 0.3535533906f, -0.3535533906f, -0.3535533906f,  0.3535533906f },
        { 0.1913417162f, -0.4619397663f,  0.4619397663f, -0.1913417162f }
    };
    constexpr float CO[4][4] = {
        { 0.4903926402f,  0.4157348062f,  0.2777851165f,  0.0975451610f },
        { 0.4157348062f, -0.0975451610f, -0.4903926402f, -0.2777851165f },
        { 0.2777851165f, -0.4903926402f,  0.0975451610f,  0.4157348062f },
        { 0.0975451610f, -0.2777851165f,  0.4157348062f, -0.4903926402f }
    };

    __shared__ float2 qlds[64];            // {q, 1/q}
    __shared__ float tr[256 * LDS_PITCH];

    const int tid = threadIdx.x;

    // Every wave writes the full table (identical values) -> no barrier:
    // each wave depends only on its OWN writes (in-wave lgkmcnt ordering).
    {
        int q = qual[0];
        double sd = (q < 50) ? (5000.0 / (double)q) : (200.0 - 2.0 * (double)q);
        float scale = (float)sd;
        int e = tid & 63;
        float v = c_qbase[e] * scale / 100.0f;
        v = fminf(fmaxf(v, 1.0f), 255.0f);
        qlds[e] = make_float2(v, 1.0f / v);
    }

    const int gt  = blockIdx.x * 256 + tid;       // global (block,row) id
    const int b   = gt >> 3;                      // 8x8-block index
    const int r   = gt & 7;                       // row within block
    const int img = b >> 12;                      // 64*64 blocks per 512x512 plane
    const int by  = (b >> 6) & 63;
    const int bx  = b & 63;
    const long rowaddr = (((long)img * 512 + (long)by * 8 + r) * 512) + (long)bx * 8;

    // load row r, subtract 0.5
    float x[8];
    {
        const float4 a  = *reinterpret_cast<const float4*>(in + rowaddr);
        const float4 b4 = *reinterpret_cast<const float4*>(in + rowaddr + 4);
        x[0] = a.x - 0.5f; x[1] = a.y - 0.5f; x[2] = a.z - 0.5f; x[3] = a.w - 0.5f;
        x[4] = b4.x - 0.5f; x[5] = b4.y - 0.5f; x[6] = b4.z - 0.5f; x[7] = b4.w - 0.5f;
    }

    // my quant column: {q,rq}[k][r] for k=0..7
    float qk[8], rqk[8];
#pragma unroll
    for (int k = 0; k < 8; ++k) {
        float2 t2 = qlds[k * 8 + r];
        qk[k] = t2.x; rqk[k] = t2.y;
    }

    // Stage A: u[l] = (X D^T)[r][l] via even/odd butterfly
    float u[8];
    {
        float e[4], o[4];
#pragma unroll
        for (int j = 0; j < 4; ++j) { e[j] = x[j] + x[7 - j]; o[j] = x[j] - x[7 - j]; }
#pragma unroll
        for (int m = 0; m < 4; ++m) {
            float se = 0.0f, so = 0.0f;
#pragma unroll
            for (int j = 0; j < 4; ++j) {
                se = fmaf(e[j], CE[m][j], se);
                so = fmaf(o[j], CO[m][j], so);
            }
            u[2 * m] = se; u[2 * m + 1] = so;
        }
    }

    // Transpose 1 (wave-private LDS slice; conflict-free both directions)
    const int base_w = tid * LDS_PITCH;
    const int base_r = (tid & ~7) * LDS_PITCH;
#pragma unroll
    for (int j = 0; j < 8; ++j) tr[base_w + j] = u[j];
    float t[8];
#pragma unroll
    for (int j = 0; j < 8; ++j) t[j] = tr[base_r + j * LDS_PITCH + r];  // t[j] = U[j][r]

    // Stage B: y[k] = (D U)[k][r] via butterfly; quantize with rcp-mul
    float y[8];
    {
        float e[4], o[4];
#pragma unroll
        for (int j = 0; j < 4; ++j) { e[j] = t[j] + t[7 - j]; o[j] = t[j] - t[7 - j]; }
#pragma unroll
        for (int m = 0; m < 4; ++m) {
            float se = 0.0f, so = 0.0f;
#pragma unroll
            for (int j = 0; j < 4; ++j) {
                se = fmaf(e[j], CE[m][j], se);
                so = fmaf(o[j], CO[m][j], so);
            }
            y[2 * m]     = rintf(se * rqk[2 * m])     * qk[2 * m];
            y[2 * m + 1] = rintf(so * rqk[2 * m + 1]) * qk[2 * m + 1];
        }
    }

    // Stage C1: v[j] = (D^T Yq)[j][r] via butterfly (symmetry in column j)
    float v[8];
#pragma unroll
    for (int j = 0; j < 4; ++j) {
        float a = 0.0f, bb = 0.0f;
#pragma unroll
        for (int m = 0; m < 4; ++m) {
            a  = fmaf(y[2 * m],     CE[m][j], a);
            bb = fmaf(y[2 * m + 1], CO[m][j], bb);
        }
        v[j] = a + bb; v[7 - j] = a - bb;
    }

    // Transpose 2
#pragma unroll
    for (int j = 0; j < 8; ++j) tr[base_w + j] = v[j];
    float w[8];
#pragma unroll
    for (int j = 0; j < 8; ++j) w[j] = tr[base_r + j * LDS_PITCH + r];  // w[j] = V[r][j]

    // Stage C2: s[c] = (V D)[r][c] via butterfly, +0.5, clip, store
    float srow[8];
#pragma unroll
    for (int j = 0; j < 4; ++j) {
        float a = 0.0f, bb = 0.0f;
#pragma unroll
        for (int m = 0; m < 4; ++m) {
            a  = fmaf(w[2 * m],     CE[m][j], a);
            bb = fmaf(w[2 * m + 1], CO[m][j], bb);
        }
        float s0 = a + bb + 0.5f;
        float s1 = a - bb + 0.5f;
        srow[j]     = fminf(fmaxf(s0, 0.0f), 1.0f);
        srow[7 - j] = fminf(fmaxf(s1, 0.0f), 1.0f);
    }
    *reinterpret_cast<float4*>(out + rowaddr)     = make_float4(srow[0], srow[1], srow[2], srow[3]);
    *reinterpret_cast<float4*>(out + rowaddr + 4) = make_float4(srow[4], srow[5], srow[6], srow[7]);
}

extern "C" void kernel_launch(void* const* d_in, const int* in_sizes, int n_in,
                              void* d_out, int out_size, void* d_ws, size_t ws_size,
                              hipStream_t stream) {
    const float* img  = (const float*)d_in[0];
    const int*   qual = (const int*)d_in[1];
    float*       out  = (float*)d_out;

    const int nthreads_total = (out_size / 64) * 8;   // 8 threads per 8x8 block
    const int block = 256;
    const int grid = nthreads_total / block;          // 12288

    jpeg_row_kernel<<<grid, block, 0, stream>>>(img, qual, out);
}

// Round 6
// 35.862 us; speedup vs baseline: 1.2254x; 1.0789x over previous
//
#include <hip/hip_runtime.h>

// DifferentiableJPEG forward on MI355X — round 6.
// Persistent-grid version: 2048 WGs (8/CU, full 32-wave residency), each thread
// processes 6 row-groups with a constant address stride (16 image planes), with
// next-iteration global loads prefetched under the current iteration's compute.
// Per-iteration: butterfly DCT/IDCT, rcp-mul quantize, in-wave LDS transposes
// (pitch 9, conflict-free, barrier-free), regular float4 stores.

typedef float v4f __attribute__((ext_vector_type(4)));

static __device__ __constant__ float c_qbase[64] = {
    16.f, 11.f, 10.f, 16.f, 24.f, 40.f, 51.f, 61.f,
    12.f, 12.f, 14.f, 19.f, 26.f, 58.f, 60.f, 55.f,
    14.f, 13.f, 16.f, 24.f, 40.f, 57.f, 69.f, 56.f,
    14.f, 17.f, 22.f, 29.f, 51.f, 87.f, 80.f, 62.f,
    18.f, 22.f, 37.f, 56.f, 68.f, 109.f, 103.f, 77.f,
    24.f, 35.f, 55.f, 64.f, 81.f, 104.f, 113.f, 92.f,
    49.f, 64.f, 78.f, 87.f, 103.f, 121.f, 120.f, 101.f,
    72.f, 92.f, 95.f, 98.f, 112.f, 100.f, 103.f, 99.f
};

#define LDS_PITCH 9   // write bank = 9t mod 32 (gcd(9,32)=1) -> 2-way max (free)
#define NITER 6       // 3145728 row-threads / (2048 WG * 256) = 6

__global__ __launch_bounds__(256, 8)
void jpeg_persist_kernel(const float* __restrict__ in, const int* __restrict__ qual,
                         float* __restrict__ out) {
    constexpr float CE[4][4] = {
        { 0.3535533906f,  0.3535533906f,  0.3535533906f,  0.3535533906f },
        { 0.4619397663f,  0.1913417162f, -0.1913417162f, -0.4619397663f },
        { 0.3535533906f, -0.3535533906f, -0.3535533906f,  0.3535533906f },
        { 0.1913417162f, -0.4619397663f,  0.4619397663f, -0.1913417162f }
    };
    constexpr float CO[4][4] = {
        { 0.4903926402f,  0.4157348062f,  0.2777851165f,  0.0975451610f },
        { 0.4157348062f, -0.0975451610f, -0.4903926402f, -0.2777851165f },
        { 0.2777851165f, -0.4903926402f,  0.0975451610f,  0.4157348062f },
        { 0.0975451610f, -0.2777851165f,  0.4157348062f, -0.4903926402f }
    };

    __shared__ float2 qlds[64];            // {q, 1/q}
    __shared__ float tr[256 * LDS_PITCH];

    const int tid = threadIdx.x;

    // Every wave writes the full table (identical values) -> barrier-free.
    {
        int q = qual[0];
        double sd = (q < 50) ? (5000.0 / (double)q) : (200.0 - 2.0 * (double)q);
        float scale = (float)sd;
        int e = tid & 63;
        float v = c_qbase[e] * scale / 100.0f;
        v = fminf(fmaxf(v, 1.0f), 255.0f);
        qlds[e] = make_float2(v, 1.0f / v);
    }

    const int gt  = blockIdx.x * 256 + tid;   // initial (block,row) id
    const int b   = gt >> 3;
    const int r   = gt & 7;                   // loop-invariant (stride % 8 == 0)
    const int img = b >> 12;
    const int by  = (b >> 6) & 63;
    const int bx  = b & 63;
    long addr = (((long)img * 512 + (long)by * 8 + r) * 512) + (long)bx * 8;
    const long step = 16L * 512 * 512;        // stride advances exactly 16 planes

    // loop-invariant quant column {q,1/q}[k][r]
    float qk[8], rqk[8];
#pragma unroll
    for (int k = 0; k < 8; ++k) {
        float2 t2 = qlds[k * 8 + r];
        qk[k] = t2.x; rqk[k] = t2.y;
    }

    const int base_w = tid * LDS_PITCH;
    const int base_r = (tid & ~7) * LDS_PITCH;

    float4 a  = *reinterpret_cast<const float4*>(in + addr);
    float4 b4 = *reinterpret_cast<const float4*>(in + addr + 4);

#pragma unroll
    for (int it = 0; it < NITER; ++it) {
        // consume current loads into x, then immediately prefetch next iteration
        float x[8];
        x[0] = a.x - 0.5f; x[1] = a.y - 0.5f; x[2] = a.z - 0.5f; x[3] = a.w - 0.5f;
        x[4] = b4.x - 0.5f; x[5] = b4.y - 0.5f; x[6] = b4.z - 0.5f; x[7] = b4.w - 0.5f;
        if (it + 1 < NITER) {
            a  = *reinterpret_cast<const float4*>(in + addr + step);
            b4 = *reinterpret_cast<const float4*>(in + addr + step + 4);
        }

        // Stage A: u[l] = (X D^T)[r][l] via even/odd butterfly
        float u[8];
        {
            float e[4], o[4];
#pragma unroll
            for (int j = 0; j < 4; ++j) { e[j] = x[j] + x[7 - j]; o[j] = x[j] - x[7 - j]; }
#pragma unroll
            for (int m = 0; m < 4; ++m) {
                float se = 0.0f, so = 0.0f;
#pragma unroll
                for (int j = 0; j < 4; ++j) {
                    se = fmaf(e[j], CE[m][j], se);
                    so = fmaf(o[j], CO[m][j], so);
                }
                u[2 * m] = se; u[2 * m + 1] = so;
            }
        }

        // Transpose 1 (wave-private slice; b128 writes, conflict-free)
        *reinterpret_cast<v4f*>(&tr[base_w])     = *reinterpret_cast<v4f*>(&u[0]);
        *reinterpret_cast<v4f*>(&tr[base_w + 4]) = *reinterpret_cast<v4f*>(&u[4]);
        float t[8];
#pragma unroll
        for (int j = 0; j < 8; ++j) t[j] = tr[base_r + j * LDS_PITCH + r];

        // Stage B: y[k] = (D U)[k][r] via butterfly; rcp-mul quantize
        float y[8];
        {
            float e[4], o[4];
#pragma unroll
            for (int j = 0; j < 4; ++j) { e[j] = t[j] + t[7 - j]; o[j] = t[j] - t[7 - j]; }
#pragma unroll
            for (int m = 0; m < 4; ++m) {
                float se = 0.0f, so = 0.0f;
#pragma unroll
                for (int j = 0; j < 4; ++j) {
                    se = fmaf(e[j], CE[m][j], se);
                    so = fmaf(o[j], CO[m][j], so);
                }
                y[2 * m]     = rintf(se * rqk[2 * m])     * qk[2 * m];
                y[2 * m + 1] = rintf(so * rqk[2 * m + 1]) * qk[2 * m + 1];
            }
        }

        // Stage C1: v[j] = (D^T Yq)[j][r] via symmetry
        float v[8];
#pragma unroll
        for (int j = 0; j < 4; ++j) {
            float sa = 0.0f, sb = 0.0f;
#pragma unroll
            for (int m = 0; m < 4; ++m) {
                sa = fmaf(y[2 * m],     CE[m][j], sa);
                sb = fmaf(y[2 * m + 1], CO[m][j], sb);
            }
            v[j] = sa + sb; v[7 - j] = sa - sb;
        }

        // Transpose 2
        *reinterpret_cast<v4f*>(&tr[base_w])     = *reinterpret_cast<v4f*>(&v[0]);
        *reinterpret_cast<v4f*>(&tr[base_w + 4]) = *reinterpret_cast<v4f*>(&v[4]);
        float w[8];
#pragma unroll
        for (int j = 0; j < 8; ++j) w[j] = tr[base_r + j * LDS_PITCH + r];

        // Stage C2: s[c] = (V D)[r][c] via symmetry, +0.5, clip, store
        float srow[8];
#pragma unroll
        for (int j = 0; j < 4; ++j) {
            float sa = 0.0f, sb = 0.0f;
#pragma unroll
            for (int m = 0; m < 4; ++m) {
                sa = fmaf(w[2 * m],     CE[m][j], sa);
                sb = fmaf(w[2 * m + 1], CO[m][j], sb);
            }
            float s0 = sa + sb + 0.5f;
            float s1 = sa - sb + 0.5f;
            srow[j]     = fminf(fmaxf(s0, 0.0f), 1.0f);
            srow[7 - j] = fminf(fmaxf(s1, 0.0f), 1.0f);
        }
        *reinterpret_cast<float4*>(out + addr)     = make_float4(srow[0], srow[1], srow[2], srow[3]);
        *reinterpret_cast<float4*>(out + addr + 4) = make_float4(srow[4], srow[5], srow[6], srow[7]);

        addr += step;
    }
}

extern "C" void kernel_launch(void* const* d_in, const int* in_sizes, int n_in,
                              void* d_out, int out_size, void* d_ws, size_t ws_size,
                              hipStream_t stream) {
    const float* img  = (const float*)d_in[0];
    const int*   qual = (const int*)d_in[1];
    float*       out  = (float*)d_out;

    // total row-threads = (out_size/64)*8 = 3145728 = 2048 WG * 256 thr * 6 iter
    const int grid = 2048;
    jpeg_persist_kernel<<<grid, 256, 0, stream>>>(img, qual, out);
}

// Round 7
// 35.621 us; speedup vs baseline: 1.2337x; 1.0067x over previous
//
#include <hip/hip_runtime.h>

// DifferentiableJPEG forward on MI355X — round 7: half-row threads.
// 16 threads per 8x8 block; thread (r,B,h) owns one float4 (row r, cols 4h..4h+3).
// Every global load/store instruction is lane-linear (8 x 128B contiguous
// segments, ideal 16 line-touches/KB) — vs round 6's 32/KB scatter.
// Even/odd butterfly halves split across lane pairs, exchanged via quad-perm
// DPP (xor-1). Coefficient matrix CMab[m][i] = h ? -CO[m][3-i] : CE[m][i]
// absorbs all sign/reversal asymmetry -> zero per-lane selects in any stage.
// LDS transposes: layout [B][k][c] pitch 9, all 4 instr patterns 2-way max (free).
// Persistent 2048 WGs x 256, 12 iterations, constant stride 8 planes, 1-deep prefetch.

static __device__ __constant__ float c_qbase[64] = {
    16.f, 11.f, 10.f, 16.f, 24.f, 40.f, 51.f, 61.f,
    12.f, 12.f, 14.f, 19.f, 26.f, 58.f, 60.f, 55.f,
    14.f, 13.f, 16.f, 24.f, 40.f, 57.f, 69.f, 56.f,
    14.f, 17.f, 22.f, 29.f, 51.f, 87.f, 80.f, 62.f,
    18.f, 22.f, 37.f, 56.f, 68.f, 109.f, 103.f, 77.f,
    24.f, 35.f, 55.f, 64.f, 81.f, 104.f, 113.f, 92.f,
    49.f, 64.f, 78.f, 87.f, 103.f, 121.f, 120.f, 101.f,
    72.f, 92.f, 95.f, 98.f, 112.f, 100.f, 103.f, 99.f
};

#define NITER 12

__device__ __forceinline__ float lane_xor1(float v) {
    int i = __builtin_bit_cast(int, v);
    // quad_perm {1,0,3,2} = 0xB1 : lane L <-> lane L^1 (same quad, all lanes active)
    i = __builtin_amdgcn_update_dpp(i, i, 0xB1, 0xF, 0xF, false);
    return __builtin_bit_cast(float, i);
}

__global__ __launch_bounds__(256, 8)
void jpeg_half_kernel(const float* __restrict__ in, const int* __restrict__ qual,
                      float* __restrict__ out) {
    constexpr float CE[4][4] = {
        { 0.3535533906f,  0.3535533906f,  0.3535533906f,  0.3535533906f },
        { 0.4619397663f,  0.1913417162f, -0.1913417162f, -0.4619397663f },
        { 0.3535533906f, -0.3535533906f, -0.3535533906f,  0.3535533906f },
        { 0.1913417162f, -0.4619397663f,  0.4619397663f, -0.1913417162f }
    };
    constexpr float CO[4][4] = {
        { 0.4903926402f,  0.4157348062f,  0.2777851165f,  0.0975451610f },
        { 0.4157348062f, -0.0975451610f, -0.4903926402f, -0.2777851165f },
        { 0.2777851165f, -0.4903926402f,  0.0975451610f,  0.4157348062f },
        { 0.0975451610f, -0.2777851165f,  0.4157348062f, -0.4903926402f }
    };

    __shared__ float2 qlds[64];            // {q, 1/q}
    __shared__ float tr[4 * 288];          // 4 waves x (4 blocks x 8 x 9)

    const int tid = threadIdx.x;

    // barrier-free quant table: every wave writes all 64 entries (same values)
    {
        int q = qual[0];
        double sd = (q < 50) ? (5000.0 / (double)q) : (200.0 - 2.0 * (double)q);
        float scale = (float)sd;
        int e = tid & 63;
        float v = c_qbase[e] * scale / 100.0f;
        v = fminf(fmaxf(v, 1.0f), 255.0f);
        qlds[e] = make_float2(v, 1.0f / v);
    }

    const int wave = tid >> 6;
    const int t    = tid & 63;
    const int h    = t & 1;                // half: 0 = even-freq role, 1 = odd-freq role
    const int B    = (t >> 1) & 3;         // block within wave (4 blocks/wave)
    const int rc   = t >> 3;               // image row (stages A,C2) / column (stages B,C1)
    const float sgn  = h ? -1.0f : 1.0f;
    const float msgn = -sgn;

    // coefficient matrix absorbing sign+reversal for the odd half (see header)
    float CM[4][4];
#pragma unroll
    for (int m = 0; m < 4; ++m)
#pragma unroll
        for (int i = 0; i < 4; ++i)
            CM[m][i] = h ? -CO[m][3 - i] : CE[m][i];

    // per-thread quant pairs: row/col (2m+h, rc)
    float q4[4], rq4[4];
#pragma unroll
    for (int m = 0; m < 4; ++m) {
        float2 p = qlds[(2 * m + h) * 8 + rc];
        q4[m] = p.x; rq4[m] = p.y;
    }

    // loop-invariant LDS bases (layout idx(B,k,c) = B*72 + k*9 + c, wave-private)
    const int wB    = wave * 288 + B * 72;
    const int baseA = wB + rc * 9 + h;      // T1-write / T2-read: + 2m
    const int baseB = wB + 36 * h + rc;     // T1-read  / T2-write: + 9j

    // global addressing: block = (bid*4 + wave)*4 + B ; advance 8 planes/iter
    const int blk = (blockIdx.x * 4 + wave) * 4 + B;
    const int img = blk >> 12;
    const int by  = (blk >> 6) & 63;
    const int bx  = blk & 63;
    long addr = ((long)(img * 512 + by * 8 + rc)) * 512 + bx * 8 + h * 4;
    const long step = 8L * 512 * 512;

    float4 ld = *reinterpret_cast<const float4*>(in + addr);

#pragma unroll
    for (int it = 0; it < NITER; ++it) {
        float xm[4] = { ld.x - 0.5f, ld.y - 0.5f, ld.z - 0.5f, ld.w - 0.5f };
        if (it + 1 < NITER)
            ld = *reinterpret_cast<const float4*>(in + addr + step);

        // ---- Stage A: row butterfly; h=0 -> e[i], h=1 -> -o[3-i]
        float rex[4], g[4], u[4];
#pragma unroll
        for (int i = 0; i < 4; ++i) rex[i] = lane_xor1(xm[i]);
#pragma unroll
        for (int i = 0; i < 4; ++i) g[i] = fmaf(sgn, rex[3 - i], xm[i]);
#pragma unroll
        for (int m = 0; m < 4; ++m) {
            float s = 0.0f;
#pragma unroll
            for (int i = 0; i < 4; ++i) s = fmaf(g[i], CM[m][i], s);
            u[m] = s;                       // U[rc][2m+h]
        }

        // ---- Transpose 1: write U[rc][2m+h], read U[4h+j][rc]
#pragma unroll
        for (int m = 0; m < 4; ++m) tr[baseA + 2 * m] = u[m];
        float t4[4];
#pragma unroll
        for (int j = 0; j < 4; ++j) t4[j] = tr[baseB + 9 * j];

        // ---- Stage B: column butterfly + quantize; yq[m] = quantized Y[2m+h][rc]
#pragma unroll
        for (int j = 0; j < 4; ++j) rex[j] = lane_xor1(t4[j]);
#pragma unroll
        for (int j = 0; j < 4; ++j) g[j] = fmaf(sgn, rex[3 - j], t4[j]);
        float yq[4];
#pragma unroll
        for (int m = 0; m < 4; ++m) {
            float s = 0.0f;
#pragma unroll
            for (int j = 0; j < 4; ++j) s = fmaf(g[j], CM[m][j], s);
            yq[m] = rintf(s * rq4[m]) * q4[m];
        }

        // ---- Stage C1: pjt[j] = sum_m yq[m]*CM[m][j]  (h=0: A[j], h=1: -Bo[3-j])
        float pjt[4], vr[4];
#pragma unroll
        for (int j = 0; j < 4; ++j) {
            float s = 0.0f;
#pragma unroll
            for (int m = 0; m < 4; ++m) s = fmaf(yq[m], CM[m][j], s);
            pjt[j] = s;
        }
#pragma unroll
        for (int j = 0; j < 4; ++j) rex[j] = lane_xor1(pjt[j]);
#pragma unroll
        for (int j = 0; j < 4; ++j) vr[j] = fmaf(msgn, rex[3 - j], pjt[j]);
        // h=0: vr[j] = V[j][rc] ; h=1: vr[j] = V[4+j][rc]

        // ---- Transpose 2: write V[4h+j][rc], read V[rc][2m+h]
#pragma unroll
        for (int j = 0; j < 4; ++j) tr[baseB + 9 * j] = vr[j];
        float w4[4];
#pragma unroll
        for (int m = 0; m < 4; ++m) w4[m] = tr[baseA + 2 * m];

        // ---- Stage C2: p2[d] = sum_m w4[m]*CM[m][d] (h=0: sa[d], h=1: -sb[3-d])
        float p2[4], px[4];
#pragma unroll
        for (int d = 0; d < 4; ++d) {
            float s = 0.0f;
#pragma unroll
            for (int m = 0; m < 4; ++m) s = fmaf(w4[m], CM[m][d], s);
            p2[d] = s;
        }
#pragma unroll
        for (int d = 0; d < 4; ++d) px[d] = lane_xor1(p2[d]);
        float F[4];
#pragma unroll
        for (int d = 0; d < 4; ++d) {
            // h=0: p2[d]-px[3-d] = sa[d]+sb[d] = s[d] ; h=1: p2[d]+px[3-d] = sa[3-d]-sb[3-d] = s[4+d]
            float s = fmaf(msgn, px[3 - d], p2[d]) + 0.5f;
            F[d] = fminf(fmaxf(s, 0.0f), 1.0f);
        }

        *reinterpret_cast<float4*>(out + addr) = make_float4(F[0], F[1], F[2], F[3]);
        addr += step;
    }
}

extern "C" void kernel_launch(void* const* d_in, const int* in_sizes, int n_in,
                              void* d_out, int out_size, void* d_ws, size_t ws_size,
                              hipStream_t stream) {
    const float* img  = (const float*)d_in[0];
    const int*   qual = (const int*)d_in[1];
    float*       out  = (float*)d_out;

    // 393216 blocks x 16 threads = 6291456 = 2048 WG x 256 thr x 12 iter
    jpeg_half_kernel<<<2048, 256, 0, stream>>>(img, qual, out);
}